// Round 2
// baseline (1805.321 us; speedup 1.0000x reference)
//
#include <hip/hip_runtime.h>
#include <math.h>

#define W_    64
#define WLEN_ 129
#define H_    1024
#define B_    32
#define T_    512
#define SPAD_ 641
#define H2_   512
#define EPSV  1e-14f

__device__ __forceinline__ float4 f4fma(float4 c, float4 x, float s) {
    c.x += x.x * s; c.y += x.y * s; c.z += x.z * s; c.w += x.w * s; return c;
}

// ---------------------------------------------------------------------------
// Kernel 1: fused MLP -> p, start.  hidden = tanh(dec @ w1 + b1); logit = hidden@w2 + b2
// p = 64 + len*sigmoid(logit); start = rint(p - 64).
// Grid: 256 blocks x 512 threads. Each block: 64 rows (m = t*32 + b), full N=512 via 4 chunks of 128.
// ---------------------------------------------------------------------------
__global__ __launch_bounds__(512) void mlp_kernel(
    const float* __restrict__ dec, const float* __restrict__ w1,
    const float* __restrict__ b1,  const float* __restrict__ w2,
    const float* __restrict__ b2,  const int* __restrict__ lengths,
    float* __restrict__ p_ws, int* __restrict__ start_ws)
{
    __shared__ float Ash[32][68];    // A^T tile: [kk][row], 64 rows
    __shared__ float Bsh[32][132];   // B tile: [kk][col], 128 cols
    __shared__ float rowsum[64];

    const int tid = threadIdx.x;
    const int m0  = blockIdx.x * 64;
    const int tx  = tid & 31;        // col group (32 -> 128 cols via *4)
    const int ty  = tid >> 5;        // row group (16 -> 64 rows via *4)

    if (tid < 64) rowsum[tid] = 0.0f;

    for (int nc = 0; nc < 4; ++nc) {
        const int n0 = nc * 128;
        float4 acc[4];
        acc[0] = acc[1] = acc[2] = acc[3] = make_float4(0.f, 0.f, 0.f, 0.f);

        for (int k0 = 0; k0 < 1024; k0 += 32) {
            __syncthreads();
            // stage A^T: 64 rows x 32 k
            {
                const int row = tid >> 3, kkb = (tid & 7) << 2;
                float4 v = *(const float4*)(dec + (size_t)(m0 + row) * 1024 + k0 + kkb);
                Ash[kkb + 0][row] = v.x; Ash[kkb + 1][row] = v.y;
                Ash[kkb + 2][row] = v.z; Ash[kkb + 3][row] = v.w;
            }
            // stage B: 32 k x 128 cols
            {
                const int kk = tid >> 4, cb = (tid & 15) << 3;
                const float* src = w1 + (size_t)(k0 + kk) * 512 + n0 + cb;
                float4 v0 = *(const float4*)(src);
                float4 v1 = *(const float4*)(src + 4);
                *(float4*)&Bsh[kk][cb]     = v0;
                *(float4*)&Bsh[kk][cb + 4] = v1;
            }
            __syncthreads();
            #pragma unroll
            for (int kk = 0; kk < 32; ++kk) {
                float4 a = *(const float4*)&Ash[kk][ty << 2];
                float4 b = *(const float4*)&Bsh[kk][tx << 2];
                acc[0] = f4fma(acc[0], b, a.x);
                acc[1] = f4fma(acc[1], b, a.y);
                acc[2] = f4fma(acc[2], b, a.z);
                acc[3] = f4fma(acc[3], b, a.w);
            }
        }
        // epilogue: tanh + dot with w2, reduce across the 32 col-lanes
        const int n = n0 + (tx << 2);
        float4 b1v = *(const float4*)(b1 + n);
        float4 w2v = *(const float4*)(w2 + n);
        #pragma unroll
        for (int i = 0; i < 4; ++i) {
            float4 av = acc[i];
            float s = tanhf(av.x + b1v.x) * w2v.x + tanhf(av.y + b1v.y) * w2v.y +
                      tanhf(av.z + b1v.z) * w2v.z + tanhf(av.w + b1v.w) * w2v.w;
            #pragma unroll
            for (int o = 1; o < 32; o <<= 1) s += __shfl_xor(s, o, 32);
            if (tx == 0) rowsum[(ty << 2) + i] += s;
        }
    }
    __syncthreads();
    if (tid < 64) {
        const int m = m0 + tid;
        const float logit = rowsum[tid] + b2[0];
        const int bb = m & 31;
        const float len = (float)lengths[bb];
        const float sig = 1.0f / (1.0f + expf(-logit));
        const float pv  = 64.0f + len * sig;          // exactly reference: W + len*sig
        const float sv  = rintf(pv - 64.0f);          // reference: round(p - W), half-even
        p_ws[m] = pv;
        start_ws[m] = (int)sv;
    }
}

// ---------------------------------------------------------------------------
// Kernel 3: per (b, 32-t tile): score = h_t @ sel^T, mask, softmax * gaussian, c = a @ sel.
// Grid: dim3(16, 32) x 256 threads.
// ---------------------------------------------------------------------------
__global__ __launch_bounds__(256) void attn_kernel(
    const float* __restrict__ enc, const float* __restrict__ dec,
    const int* __restrict__ lengths, const float* __restrict__ p_ws,
    const int* __restrict__ start_ws, float* __restrict__ out)
{
    __shared__ float score[32][132];   // scores, then attention weights a
    __shared__ float selS[32][132];    // phase A: [kk][w]; phase C: [kk][col<128]
    __shared__ float htT[32][36];      // [kk][t]
    __shared__ float pt[32];
    __shared__ int   st[32];
    __shared__ int   ss_sh, len_sh;

    const int tid = threadIdx.x;
    const int b   = blockIdx.y;
    const int t0  = blockIdx.x * 32;

    if (tid < 32) {
        st[tid] = start_ws[(t0 + tid) * 32 + b];
        pt[tid] = p_ws[(t0 + tid) * 32 + b];
    }
    if (tid == 0) {
        ss_sh  = start_ws[511 * 32 + b];   // start[:, T-1]
        len_sh = lengths[b];
    }
    __syncthreads();
    const int sel0 = ss_sh;
    const int len  = len_sh;

    // ---------------- Phase A: scores (M=32 t, N=129 w, K=1024) ----------------
    const int wg = tid & 15;   // w = wg*8 .. +7
    const int tg = tid >> 4;   // t = tg*2, tg*2+1
    float4 a00 = make_float4(0,0,0,0), a01 = a00, a10 = a00, a11 = a00;
    float accT = 0.0f;         // tail column w=128, owned by tid<32 (t=tid)

    for (int k0 = 0; k0 < 1024; k0 += 32) {
        __syncthreads();
        {   // stage h_t^T: 32 t x 32 k
            const int row = tid >> 3, kkb = (tid & 7) << 2;
            float4 v = *(const float4*)(dec + ((size_t)(t0 + row) * 32 + b) * 1024 + k0 + kkb);
            htT[kkb + 0][row] = v.x; htT[kkb + 1][row] = v.y;
            htT[kkb + 2][row] = v.z; htT[kkb + 3][row] = v.w;
        }
        // stage sel: 129 w x 32 k (5 passes of 32 w)
        #pragma unroll
        for (int wp = 0; wp < 5; ++wp) {
            const int w = wp * 32 + (tid >> 3), kkb = (tid & 7) << 2;
            if (w < 129) {
                float4 v = *(const float4*)(enc + ((size_t)(sel0 + w) * 32 + b) * 1024 + k0 + kkb);
                selS[kkb + 0][w] = v.x; selS[kkb + 1][w] = v.y;
                selS[kkb + 2][w] = v.z; selS[kkb + 3][w] = v.w;
            }
        }
        __syncthreads();
        #pragma unroll
        for (int kk = 0; kk < 32; ++kk) {
            float2 hv = *(const float2*)&htT[kk][tg << 1];
            float4 s0 = *(const float4*)&selS[kk][wg << 3];
            float4 s1 = *(const float4*)&selS[kk][(wg << 3) + 4];
            a00 = f4fma(a00, s0, hv.x); a01 = f4fma(a01, s1, hv.x);
            a10 = f4fma(a10, s0, hv.y); a11 = f4fma(a11, s1, hv.y);
            if (tid < 32) accT += htT[kk][tid] * selS[kk][128];
        }
    }
    {
        const int t = tg << 1;
        *(float4*)&score[t][wg << 3]           = a00;
        *(float4*)&score[t][(wg << 3) + 4]     = a01;
        *(float4*)&score[t + 1][wg << 3]       = a10;
        *(float4*)&score[t + 1][(wg << 3) + 4] = a11;
        if (tid < 32) score[tid][128] = accT;
    }
    __syncthreads();

    // ---------------- Phase B: mask, softmax, * gaussian ----------------
    {
        const int row = tid >> 3, l8 = tid & 7;
        const int s = st[row];
        const float d = pt[row] - (float)s;       // p - start  (positions-p = w - d)
        const int lo = 64 - s;
        const int hi = len + 64 - s;
        float scv[17];
        float mx = -3.4e38f;
        #pragma unroll
        for (int q = 0; q < 17; ++q) {
            const int w = l8 + (q << 3);
            if (w < 129) {
                float v = score[row][w];
                if (w < lo || w >= hi) v = EPSV;
                scv[q] = v;
                mx = fmaxf(mx, v);
            } else scv[q] = -3.4e38f;
        }
        #pragma unroll
        for (int o = 1; o < 8; o <<= 1) mx = fmaxf(mx, __shfl_xor(mx, o, 8));
        float sum = 0.0f;
        #pragma unroll
        for (int q = 0; q < 17; ++q) {
            const int w = l8 + (q << 3);
            if (w < 129) sum += expf(scv[q] - mx);
        }
        #pragma unroll
        for (int o = 1; o < 8; o <<= 1) sum += __shfl_xor(sum, o, 8);
        const float inv = 1.0f / sum;
        #pragma unroll
        for (int q = 0; q < 17; ++q) {
            const int w = l8 + (q << 3);
            if (w < 129) {
                const float x = (float)w - d;
                const float g = expf(-(x * x) * (1.0f / 2048.0f));
                score[row][w] = expf(scv[q] - mx) * inv * g;
            }
        }
    }
    __syncthreads();

    // ---------------- Phase C: c = a @ sel, write out (T,B,H) ----------------
    const int col = (tid & 31) << 2;   // 128 cols per h-chunk
    const int ttg = tid >> 5;          // 8 groups x 4 t rows
    for (int hc = 0; hc < 8; ++hc) {
        const int h0 = hc * 128;
        float4 c0 = make_float4(0,0,0,0), c1 = c0, c2 = c0, c3 = c0;
        for (int kc = 0; kc < 5; ++kc) {
            const int kbase = kc * 32;
            const int ks = (129 - kbase) < 32 ? (129 - kbase) : 32;
            __syncthreads();
            {   // stage sel chunk: ks rows x 128 cols
                const int kkr = tid >> 3, cb = (tid & 7) << 4;
                if (kkr < ks) {
                    const float* src = enc + ((size_t)(sel0 + kbase + kkr) * 32 + b) * 1024 + h0 + cb;
                    #pragma unroll
                    for (int q = 0; q < 4; ++q)
                        *(float4*)&selS[kkr][cb + (q << 2)] = *(const float4*)(src + (q << 2));
                }
            }
            __syncthreads();
            for (int kk = 0; kk < ks; ++kk) {
                float4 sv = *(const float4*)&selS[kk][col];
                const int k = kbase + kk;
                c0 = f4fma(c0, sv, score[(ttg << 2) + 0][k]);
                c1 = f4fma(c1, sv, score[(ttg << 2) + 1][k]);
                c2 = f4fma(c2, sv, score[(ttg << 2) + 2][k]);
                c3 = f4fma(c3, sv, score[(ttg << 2) + 3][k]);
            }
        }
        float4 cc[4] = {c0, c1, c2, c3};
        #pragma unroll
        for (int i = 0; i < 4; ++i) {
            const size_t off = ((size_t)(t0 + (ttg << 2) + i) * 32 + b) * 1024 + h0 + col;
            *(float4*)(out + off) = cc[i];
        }
    }
}

extern "C" void kernel_launch(void* const* d_in, const int* in_sizes, int n_in,
                              void* d_out, int out_size, void* d_ws, size_t ws_size,
                              hipStream_t stream) {
    const float* enc = (const float*)d_in[0];
    const float* dec = (const float*)d_in[1];
    const float* w1  = (const float*)d_in[2];
    const float* b1  = (const float*)d_in[3];
    const float* w2  = (const float*)d_in[4];
    const float* b2  = (const float*)d_in[5];
    const int* lengths = (const int*)d_in[6];

    float* p_ws     = (float*)d_ws;
    int*   start_ws = (int*)((char*)d_ws + 16384 * sizeof(float));
    float* out      = (float*)d_out;

    mlp_kernel<<<256, 512, 0, stream>>>(dec, w1, b1, w2, b2, lengths, p_ws, start_ws);
    attn_kernel<<<dim3(16, 32), 256, 0, stream>>>(enc, dec, lengths, p_ws, start_ws, out);
}

// Round 4
// 476.943 us; speedup vs baseline: 3.7852x; 3.7852x over previous
//
#include <hip/hip_runtime.h>
#include <math.h>

#define EPSV 1e-14f

typedef short s8b __attribute__((ext_vector_type(8)));
typedef float f32x4 __attribute__((ext_vector_type(4)));

__device__ __forceinline__ unsigned int bf16rne(float x) {
    unsigned int u = __float_as_uint(x);
    return (u + 0x7FFFu + ((u >> 16) & 1u)) >> 16;
}
// pack truncated-bf16(x), truncated-bf16(y) into one u32 (x in low half)
__device__ __forceinline__ unsigned int pack_hi2(unsigned int xu, unsigned int yu) {
    return __builtin_amdgcn_perm(yu, xu, 0x07060302u);
}
// split float4 into trunc-hi bf16x4 and trunc-lo bf16x4 (packed as uint2 each)
__device__ __forceinline__ void split4(float4 f, uint2& hi, uint2& lo) {
    unsigned int ux = __float_as_uint(f.x), uy = __float_as_uint(f.y);
    unsigned int uz = __float_as_uint(f.z), uw = __float_as_uint(f.w);
    hi.x = pack_hi2(ux, uy);
    hi.y = pack_hi2(uz, uw);
    float rx = f.x - __uint_as_float(ux & 0xFFFF0000u);
    float ry = f.y - __uint_as_float(uy & 0xFFFF0000u);
    float rz = f.z - __uint_as_float(uz & 0xFFFF0000u);
    float rw = f.w - __uint_as_float(uw & 0xFFFF0000u);
    lo.x = pack_hi2(__float_as_uint(rx), __float_as_uint(ry));
    lo.y = pack_hi2(__float_as_uint(rz), __float_as_uint(rw));
}

// ---------------------------------------------------------------------------
// Kernel 1: fused MLP -> p, start (fp32, unchanged math; + register prefetch).
// ---------------------------------------------------------------------------
__global__ __launch_bounds__(512) void mlp_kernel(
    const float* __restrict__ dec, const float* __restrict__ w1,
    const float* __restrict__ b1,  const float* __restrict__ w2,
    const float* __restrict__ b2,  const int* __restrict__ lengths,
    float* __restrict__ p_ws, int* __restrict__ start_ws)
{
    __shared__ float Ash[32][68];
    __shared__ float Bsh[32][132];
    __shared__ float rowsum[64];

    const int tid = threadIdx.x;
    const int m0  = blockIdx.x * 64;
    const int tx  = tid & 31;
    const int ty  = tid >> 5;

    if (tid < 64) rowsum[tid] = 0.0f;

    const int arow = tid >> 3, akkb = (tid & 7) << 2;
    const int bkk  = tid >> 4, bcb  = (tid & 15) << 3;
    const float* asrc = dec + (size_t)(m0 + arow) * 1024 + akkb;

    float4 pa  = *(const float4*)(asrc);
    float4 pb0 = *(const float4*)(w1 + (size_t)bkk * 512 + bcb);
    float4 pb1 = *(const float4*)(w1 + (size_t)bkk * 512 + bcb + 4);

    for (int nc = 0; nc < 4; ++nc) {
        const int n0 = nc * 128;
        float4 acc[4];
        acc[0] = acc[1] = acc[2] = acc[3] = make_float4(0.f, 0.f, 0.f, 0.f);

        for (int ki = 0; ki < 32; ++ki) {
            __syncthreads();
            Ash[akkb + 0][arow] = pa.x; Ash[akkb + 1][arow] = pa.y;
            Ash[akkb + 2][arow] = pa.z; Ash[akkb + 3][arow] = pa.w;
            *(float4*)&Bsh[bkk][bcb]     = pb0;
            *(float4*)&Bsh[bkk][bcb + 4] = pb1;
            {
                const int it = nc * 32 + ki + 1;
                if (it < 128) {
                    const int nc2 = it >> 5, k2 = (it & 31) << 5;
                    pa = *(const float4*)(asrc + k2);
                    const float* bs = w1 + (size_t)(k2 + bkk) * 512 + nc2 * 128 + bcb;
                    pb0 = *(const float4*)bs;
                    pb1 = *(const float4*)(bs + 4);
                }
            }
            __syncthreads();
            #pragma unroll
            for (int kk = 0; kk < 32; ++kk) {
                float4 a = *(const float4*)&Ash[kk][ty << 2];
                float4 b = *(const float4*)&Bsh[kk][tx << 2];
                acc[0].x += b.x * a.x; acc[0].y += b.y * a.x; acc[0].z += b.z * a.x; acc[0].w += b.w * a.x;
                acc[1].x += b.x * a.y; acc[1].y += b.y * a.y; acc[1].z += b.z * a.y; acc[1].w += b.w * a.y;
                acc[2].x += b.x * a.z; acc[2].y += b.y * a.z; acc[2].z += b.z * a.z; acc[2].w += b.w * a.z;
                acc[3].x += b.x * a.w; acc[3].y += b.y * a.w; acc[3].z += b.z * a.w; acc[3].w += b.w * a.w;
            }
        }
        const int n = n0 + (tx << 2);
        float4 b1v = *(const float4*)(b1 + n);
        float4 w2v = *(const float4*)(w2 + n);
        #pragma unroll
        for (int i = 0; i < 4; ++i) {
            float4 av = acc[i];
            float s = tanhf(av.x + b1v.x) * w2v.x + tanhf(av.y + b1v.y) * w2v.y +
                      tanhf(av.z + b1v.z) * w2v.z + tanhf(av.w + b1v.w) * w2v.w;
            #pragma unroll
            for (int o = 1; o < 32; o <<= 1) s += __shfl_xor(s, o, 32);
            if (tx == 0) rowsum[(ty << 2) + i] += s;
        }
    }
    __syncthreads();
    if (tid < 64) {
        const int m = m0 + tid;
        const float logit = rowsum[tid] + b2[0];
        const float len = (float)lengths[m & 31];
        const float sig = 1.0f / (1.0f + expf(-logit));
        const float pv  = 64.0f + len * sig;
        const float sv  = rintf(pv - 64.0f);
        p_ws[m] = pv;
        start_ws[m] = (int)sv;
    }
}

// ---------------------------------------------------------------------------
// Kernel 2: selT[b][h][w] = bf16(enc[sel0_b + w][b][h]), w padded 129->136 with 0.
// Grid (16 h-chunks, 32 b) x 256.
// FIX R4: store loop now covers all 34 uint2-groups per h-row (w 0..135);
// previous version's `c = tid & 31` left w=128..135 unwritten (ws poison),
// silently dropping the w=128 tail term in PV -> absmax 0.62.
// ---------------------------------------------------------------------------
__global__ __launch_bounds__(256) void selt_kernel(
    const float* __restrict__ enc, const int* __restrict__ start_ws,
    short* __restrict__ selT)
{
    __shared__ short lt[129][68];
    const int b = blockIdx.y, h0 = blockIdx.x * 64;
    const int tid = threadIdx.x;
    const int sel0 = start_ws[511 * 32 + b];
    const int srow = tid >> 4, scol = tid & 15;

    #pragma unroll
    for (int r = 0; r < 9; ++r) {
        const int w = r * 16 + srow;
        if (w < 129) {
            float4 v = *(const float4*)(enc + ((size_t)(sel0 + w) * 32 + b) * 1024 + h0 + scol * 4);
            unsigned int h1 = bf16rne(v.x) | (bf16rne(v.y) << 16);
            unsigned int h2 = bf16rne(v.z) | (bf16rne(v.w) << 16);
            *(uint2*)&lt[w][scol * 4] = make_uint2(h1, h2);
        }
    }
    __syncthreads();
    for (int idx = tid; idx < 64 * 34; idx += 256) {
        const int hh = idx / 34, c = idx - hh * 34;
        unsigned int lo = 0, hi = 0;
        #pragma unroll
        for (int i = 0; i < 4; ++i) {
            const int w = c * 4 + i;
            unsigned int val = (w < 129) ? (unsigned short)lt[w][hh] : 0u;
            if (i < 2) lo |= val << (16 * i); else hi |= val << (16 * (i - 2));
        }
        *(uint2*)(selT + ((size_t)b * 1024 + h0 + hh) * 136 + c * 4) = make_uint2(lo, hi);
    }
}

// ---------------------------------------------------------------------------
// Kernel 3: fused score(MFMA hi/lo x3) -> mask/softmax*gaussian -> PV(MFMA bf16).
// Grid (8 t-tiles, 32 b) x 256 (4 waves).
// LDS carve (59904 B total):
//   phase A: selhi@0(20736) sello@20736(20736) dechi@41472(9216) declo@50688(9216)
//   phase B: score f32 @0 (64x144x4=36864), a bf16 @36864 (64x152x2=19456)
//   phase C: selT tile @0 (64x136x2=17408), a stays @36864
// ---------------------------------------------------------------------------
__global__ __launch_bounds__(256, 1) void attn_kernel(
    const float* __restrict__ enc, const float* __restrict__ dec,
    const int* __restrict__ lengths, const float* __restrict__ p_ws,
    const int* __restrict__ start_ws, const short* __restrict__ selT,
    float* __restrict__ out)
{
    alignas(16) __shared__ char smem[59904];
    const int tid = threadIdx.x;
    const int b = blockIdx.y;
    const int t0 = blockIdx.x * 64;
    const int wid = tid >> 6, lane = tid & 63;
    const int lr = lane & 15, lq = lane >> 4;
    const int sel0 = start_ws[511 * 32 + b];
    const int len = lengths[b];

    short* SH = (short*)(smem);             // stride 72 shorts (144 B)
    short* SL = (short*)(smem + 20736);
    short* DH = (short*)(smem + 41472);
    short* DL = (short*)(smem + 50688);

    const int srow = tid >> 4, scol = tid & 15;
    const float* esrc = enc + (size_t)sel0 * 32768 + b * 1024 + scol * 4;
    const float* dsrc = dec + (size_t)t0 * 32768 + b * 1024 + scol * 4;

    // ---- Phase A: score = h_t . sel  (M=64 t, N=144 w (129 valid), K=1024) ----
    float4 ps[9];
    float4 pd[4];
    #pragma unroll
    for (int r = 0; r < 9; ++r) { const int row = r * 16 + srow; if (row < 129) ps[r] = *(const float4*)(esrc + (size_t)row * 32768); }
    #pragma unroll
    for (int r = 0; r < 4; ++r) { const int row = r * 16 + srow; pd[r] = *(const float4*)(dsrc + (size_t)row * 32768); }

    const int kh = wid >> 1, nh = wid & 1;
    const int nt0 = nh ? 5 : 0, ncnt = nh ? 4 : 5;

    f32x4 zero4 = {0.f, 0.f, 0.f, 0.f};
    f32x4 acc[4][5];
    #pragma unroll
    for (int m = 0; m < 4; ++m)
        #pragma unroll
        for (int n = 0; n < 5; ++n) acc[m][n] = zero4;

    for (int ks = 0; ks < 16; ++ks) {
        __syncthreads();
        #pragma unroll
        for (int r = 0; r < 9; ++r) {
            const int row = r * 16 + srow;
            if (row < 129) {
                uint2 h, l; split4(ps[r], h, l);
                *(uint2*)(SH + row * 72 + scol * 4) = h;
                *(uint2*)(SL + row * 72 + scol * 4) = l;
            }
        }
        #pragma unroll
        for (int r = 0; r < 4; ++r) {
            const int row = r * 16 + srow;
            uint2 h, l; split4(pd[r], h, l);
            *(uint2*)(DH + row * 72 + scol * 4) = h;
            *(uint2*)(DL + row * 72 + scol * 4) = l;
        }
        if (ks < 15) {
            const int k1 = (ks + 1) * 64;
            #pragma unroll
            for (int r = 0; r < 9; ++r) { const int row = r * 16 + srow; if (row < 129) ps[r] = *(const float4*)(esrc + (size_t)row * 32768 + k1); }
            #pragma unroll
            for (int r = 0; r < 4; ++r) { const int row = r * 16 + srow; pd[r] = *(const float4*)(dsrc + (size_t)row * 32768 + k1); }
        }
        __syncthreads();

        s8b ah[4], al[4];
        #pragma unroll
        for (int m = 0; m < 4; ++m) {
            const int off = (m * 16 + lr) * 72 + kh * 32 + lq * 8;
            ah[m] = *(const s8b*)(DH + off);
            al[m] = *(const s8b*)(DL + off);
        }
        #pragma unroll
        for (int ni = 0; ni < 5; ++ni) {
            if (ni < ncnt) {
                const int off = ((nt0 + ni) * 16 + lr) * 72 + kh * 32 + lq * 8;
                s8b bh = *(const s8b*)(SH + off);
                s8b bl = *(const s8b*)(SL + off);
                #pragma unroll
                for (int m = 0; m < 4; ++m) {
                    acc[m][ni] = __builtin_amdgcn_mfma_f32_16x16x32_bf16(ah[m], bh, acc[m][ni], 0, 0, 0);
                    acc[m][ni] = __builtin_amdgcn_mfma_f32_16x16x32_bf16(ah[m], bl, acc[m][ni], 0, 0, 0);
                    acc[m][ni] = __builtin_amdgcn_mfma_f32_16x16x32_bf16(al[m], bh, acc[m][ni], 0, 0, 0);
                }
            }
        }
    }

    // ---- merge k-halves into score LDS ----
    float* SC = (float*)smem;   // stride 144 floats
    __syncthreads();
    if (kh == 0) {
        #pragma unroll
        for (int m = 0; m < 4; ++m)
            #pragma unroll
            for (int ni = 0; ni < 5; ++ni) {
                if (ni < ncnt) {
                    #pragma unroll
                    for (int r = 0; r < 4; ++r)
                        SC[(m * 16 + lq * 4 + r) * 144 + (nt0 + ni) * 16 + lr] = acc[m][ni][r];
                }
            }
    }
    __syncthreads();
    if (kh == 1) {
        #pragma unroll
        for (int m = 0; m < 4; ++m)
            #pragma unroll
            for (int ni = 0; ni < 5; ++ni) {
                if (ni < ncnt) {
                    #pragma unroll
                    for (int r = 0; r < 4; ++r) {
                        const int idx = (m * 16 + lq * 4 + r) * 144 + (nt0 + ni) * 16 + lr;
                        SC[idx] += acc[m][ni][r];
                    }
                }
            }
    }
    __syncthreads();

    // ---- Phase B: mask, softmax, * gaussian -> a (bf16) ----
    short* AL = (short*)(smem + 36864);   // stride 152 shorts
    {
        const int row = tid >> 2, q = tid & 3;
        const int s_t = start_ws[(t0 + row) * 32 + b];
        const float p_t = p_ws[(t0 + row) * 32 + b];
        const float d = p_t - (float)s_t;
        const int lob = 64 - s_t, hib = len + 64 - s_t;
        float mx = -3.4e38f;
        for (int w = q; w < 129; w += 4) {
            float v = SC[row * 144 + w];
            v = (w < lob || w >= hib) ? EPSV : v;
            SC[row * 144 + w] = v;
            mx = fmaxf(mx, v);
        }
        mx = fmaxf(mx, __shfl_xor(mx, 1));
        mx = fmaxf(mx, __shfl_xor(mx, 2));
        float sum = 0.f;
        for (int w = q; w < 129; w += 4) sum += expf(SC[row * 144 + w] - mx);
        sum += __shfl_xor(sum, 1);
        sum += __shfl_xor(sum, 2);
        const float inv = 1.0f / sum;
        for (int w = q; w < 129; w += 4) {
            const float e = expf(SC[row * 144 + w] - mx);
            const float x = (float)w - d;
            const float g = expf(-(x * x) * (1.0f / 2048.0f));
            AL[row * 152 + w] = (short)bf16rne(e * inv * g);
        }
    }
    __syncthreads();

    // ---- Phase C: c = a @ sel via selT tiles ----
    const int mh = wid >> 1, nh2 = wid & 1;
    s8b PA[2][4];
    float a128f[2][4];
    #pragma unroll
    for (int mi = 0; mi < 2; ++mi) {
        const int tt = mh * 2 + mi;
        #pragma unroll
        for (int kq = 0; kq < 4; ++kq)
            PA[mi][kq] = *(const s8b*)(AL + (tt * 16 + lr) * 152 + kq * 32 + lq * 8);
        #pragma unroll
        for (int r = 0; r < 4; ++r)
            a128f[mi][r] = __uint_as_float(((unsigned int)(unsigned short)AL[(tt * 16 + lq * 4 + r) * 152 + 128]) << 16);
    }

    short* ST = (short*)smem;   // stride 136 shorts, 64 rows
    const short* stg = selT + (size_t)b * 139264;
    uint4 pv[4]; uint4 pt;
    #pragma unroll
    for (int r = 0; r < 4; ++r) { const int hh = r * 16 + srow; pv[r] = *(const uint4*)(stg + (size_t)hh * 136 + scol * 8); }
    if (tid < 64) pt = *(const uint4*)(stg + (size_t)tid * 136 + 128);

    for (int hc = 0; hc < 16; ++hc) {
        __syncthreads();
        #pragma unroll
        for (int r = 0; r < 4; ++r) { const int hh = r * 16 + srow; *(uint4*)(ST + hh * 136 + scol * 8) = pv[r]; }
        if (tid < 64) *(uint4*)(ST + tid * 136 + 128) = pt;
        if (hc < 15) {
            const size_t hoff = (size_t)(hc + 1) * 64 * 136;
            #pragma unroll
            for (int r = 0; r < 4; ++r) { const int hh = r * 16 + srow; pv[r] = *(const uint4*)(stg + hoff + (size_t)hh * 136 + scol * 8); }
            if (tid < 64) pt = *(const uint4*)(stg + hoff + (size_t)tid * 136 + 128);
        }
        __syncthreads();

        f32x4 c2[2][2];
        c2[0][0] = zero4; c2[0][1] = zero4; c2[1][0] = zero4; c2[1][1] = zero4;
        #pragma unroll
        for (int ni = 0; ni < 2; ++ni) {
            const int hr = (nh2 * 2 + ni) * 16 + lr;
            const float s128 = __uint_as_float(((unsigned int)(unsigned short)ST[hr * 136 + 128]) << 16);
            #pragma unroll
            for (int kq = 0; kq < 4; ++kq) {
                s8b bv = *(const s8b*)(ST + hr * 136 + kq * 32 + lq * 8);
                #pragma unroll
                for (int mi = 0; mi < 2; ++mi)
                    c2[mi][ni] = __builtin_amdgcn_mfma_f32_16x16x32_bf16(PA[mi][kq], bv, c2[mi][ni], 0, 0, 0);
            }
            #pragma unroll
            for (int mi = 0; mi < 2; ++mi)
                #pragma unroll
                for (int r = 0; r < 4; ++r)
                    c2[mi][ni][r] += a128f[mi][r] * s128;
        }
        const int h0 = hc * 64;
        #pragma unroll
        for (int mi = 0; mi < 2; ++mi) {
            const int tbase = t0 + (mh * 2 + mi) * 16 + lq * 4;
            #pragma unroll
            for (int ni = 0; ni < 2; ++ni) {
                const int h = h0 + (nh2 * 2 + ni) * 16 + lr;
                #pragma unroll
                for (int r = 0; r < 4; ++r)
                    out[((size_t)(tbase + r) * 32 + b) * 1024 + h] = c2[mi][ni][r];
            }
        }
    }
}

extern "C" void kernel_launch(void* const* d_in, const int* in_sizes, int n_in,
                              void* d_out, int out_size, void* d_ws, size_t ws_size,
                              hipStream_t stream) {
    const float* enc = (const float*)d_in[0];
    const float* dec = (const float*)d_in[1];
    const float* w1  = (const float*)d_in[2];
    const float* b1  = (const float*)d_in[3];
    const float* w2  = (const float*)d_in[4];
    const float* b2  = (const float*)d_in[5];
    const int* lengths = (const int*)d_in[6];

    float* p_ws     = (float*)d_ws;
    int*   start_ws = (int*)((char*)d_ws + 65536);
    short* selT     = (short*)((char*)d_ws + 131072);
    float* out      = (float*)d_out;

    mlp_kernel<<<256, 512, 0, stream>>>(dec, w1, b1, w2, b2, lengths, p_ws, start_ws);
    selt_kernel<<<dim3(16, 32), 256, 0, stream>>>(enc, start_ws, selT);
    attn_kernel<<<dim3(8, 32), 256, 0, stream>>>(enc, dec, lengths, p_ws, start_ws, selT, out);
}